// Round 2
// baseline (1663.695 us; speedup 1.0000x reference)
//
#include <hip/hip_runtime.h>
#include <hip/hip_bf16.h>
#include <stdint.h>

// GraphSAGE layer, N=16384, F_IN=F_OUT=256.
// out = (adj@ (x@W1))/deg + x@W2 + bias
//   K0: WT[n][k] (bf16)  = transpose of [W1|W2]
//   K1: yTt[j/32][n][32] (bf16, K-TILED) = (x@W1)^T ; z[m][n] = x@W2 + bias
//   K2 v10b: BM=128, BK=64, split-K 2, 8 waves of 64x64 (32 MFMA/wave/step),
//          DOUBLE-buffered LDS (stride 72 hw: 16B-aligned b128, <=2-way banks),
//          double register sets (arrays, const-indexed) + counted
//          s_waitcnt vmcnt(8) (wait only the OLDEST set; loads for t+2 stay
//          in flight across 2 barriers), raw s_barrier w/ lgkmcnt(0) only,
//          setprio(1) around MFMA cluster.
//   K3: out = (p0+p1)/(d0+d1) + z

typedef short bf16x8 __attribute__((ext_vector_type(8)));
typedef float f32x4  __attribute__((ext_vector_type(4)));

__device__ __forceinline__ uint32_t pack_bf16_rne(float lo, float hi) {
    uint32_t ul = __float_as_uint(lo);
    uint32_t uh = __float_as_uint(hi);
    ul = (ul + 0x7fffu + ((ul >> 16) & 1u)) >> 16;
    uh = (uh + 0x7fffu + ((uh >> 16) & 1u)) >> 16;
    return ul | (uh << 16);
}

// ---------------- K0: transpose weight [512,256] f32 -> WT [512(n)][256(k)] bf16
__global__ __launch_bounds__(256) void k_transpose_w(const float* __restrict__ w,
                                                     uint16_t* __restrict__ wt) {
    int idx = blockIdx.x * 256 + threadIdx.x;   // 0..131071
    int n = idx >> 8;
    int k = idx & 255;
    int row = (n < 256) ? k : (256 + k);
    int col = (n < 256) ? n : (n - 256);
    uint32_t u = __float_as_uint(w[row * 256 + col]);
    u = (u + 0x7fffu + ((u >> 16) & 1u)) >> 16;
    wt[idx] = (uint16_t)u;
}

// ---------------- K1: small GEMM  [16384,256] @ [256,512]
// -> yTt (K-tiled transpose, cols 0..255) / z (cols 256..511)
__global__ __launch_bounds__(256) void k_small_gemm(const float* __restrict__ x,
                                                    const uint16_t* __restrict__ wt,
                                                    const float* __restrict__ bias,
                                                    uint16_t* __restrict__ yTt,
                                                    float* __restrict__ z) {
    __shared__ uint16_t As[128 * 32];  // [m][k] bf16
    __shared__ uint16_t Bs[128 * 32];  // [n][k] bf16

    const int t  = threadIdx.x;
    const int ct = blockIdx.x;        // 0..3
    const int rt = blockIdx.y;        // 0..127
    const int m0 = rt * 128;
    const int n0 = ct * 128;

    const int lane = t & 63, w = t >> 6;
    const int wr = w >> 1, wc = w & 1;
    const int l15 = lane & 15, quad = lane >> 4;

    f32x4 acc[4][4] = {};

    float4 a_reg[4];
    uint4  b_reg[2];

#pragma unroll
    for (int i = 0; i < 4; ++i) {
        int f4 = t + 256 * i, row = f4 >> 3, c4 = f4 & 7;
        a_reg[i] = *(const float4*)(x + (m0 + row) * 256 + c4 * 4);
    }
#pragma unroll
    for (int i = 0; i < 2; ++i) {
        int u4 = t + 256 * i, n_l = u4 >> 2, part = u4 & 3;
        b_reg[i] = *(const uint4*)(wt + (n0 + n_l) * 256 + part * 8);
    }

    for (int kk = 0; kk < 8; ++kk) {
        __syncthreads();
#pragma unroll
        for (int i = 0; i < 4; ++i) {
            int f4 = t + 256 * i, row = f4 >> 3, c4 = f4 & 7;
            uint2 p;
            p.x = pack_bf16_rne(a_reg[i].x, a_reg[i].y);
            p.y = pack_bf16_rne(a_reg[i].z, a_reg[i].w);
            *(uint2*)(As + row * 32 + c4 * 4) = p;
        }
#pragma unroll
        for (int i = 0; i < 2; ++i) {
            int u4 = t + 256 * i, n_l = u4 >> 2, part = u4 & 3;
            *(uint4*)(Bs + n_l * 32 + part * 8) = b_reg[i];
        }
        if (kk < 7) {
            int k0 = (kk + 1) * 32;
#pragma unroll
            for (int i = 0; i < 4; ++i) {
                int f4 = t + 256 * i, row = f4 >> 3, c4 = f4 & 7;
                a_reg[i] = *(const float4*)(x + (m0 + row) * 256 + k0 + c4 * 4);
            }
#pragma unroll
            for (int i = 0; i < 2; ++i) {
                int u4 = t + 256 * i, n_l = u4 >> 2, part = u4 & 3;
                b_reg[i] = *(const uint4*)(wt + (n0 + n_l) * 256 + k0 + part * 8);
            }
        }
        __syncthreads();

        bf16x8 a_frag[4], b_frag[4];
#pragma unroll
        for (int fr = 0; fr < 4; ++fr)
            a_frag[fr] = *(const bf16x8*)(As + (wr * 64 + fr * 16 + l15) * 32 + quad * 8);
#pragma unroll
        for (int fc = 0; fc < 4; ++fc)
            b_frag[fc] = *(const bf16x8*)(Bs + (wc * 64 + fc * 16 + l15) * 32 + quad * 8);
#pragma unroll
        for (int fr = 0; fr < 4; ++fr)
#pragma unroll
            for (int fc = 0; fc < 4; ++fc)
                acc[fr][fc] = __builtin_amdgcn_mfma_f32_16x16x32_bf16(
                    a_frag[fr], b_frag[fc], acc[fr][fc], 0, 0, 0);
    }

    if (ct < 2) {
        // y^T K-tiled: yTt[(m>>5)][n][32] + (m&31); lane's 4 regs = 4
        // consecutive m inside one 32-tile (m_base%32 <= 28) -> one uint2
#pragma unroll
        for (int fr = 0; fr < 4; ++fr) {
            int m_base = m0 + wr * 64 + fr * 16 + quad * 4;
#pragma unroll
            for (int fc = 0; fc < 4; ++fc) {
                int n_g = n0 + wc * 64 + fc * 16 + l15;   // 0..255
                uint2 pp;
                pp.x = pack_bf16_rne(acc[fr][fc][0], acc[fr][fc][1]);
                pp.y = pack_bf16_rne(acc[fr][fc][2], acc[fr][fc][3]);
                *(uint2*)(yTt + (size_t)(m_base >> 5) * 8192 + n_g * 32 + (m_base & 31)) = pp;
            }
        }
    } else {
#pragma unroll
        for (int fr = 0; fr < 4; ++fr) {
            int m_base = m0 + wr * 64 + fr * 16 + quad * 4;
#pragma unroll
            for (int fc = 0; fc < 4; ++fc) {
                int n_g = (n0 - 256) + wc * 64 + fc * 16 + l15;  // 0..255
                float bv = bias[n_g];
#pragma unroll
                for (int r = 0; r < 4; ++r)
                    z[(size_t)(m_base + r) * 256 + n_g] = acc[fr][fc][r] + bv;
            }
        }
    }
}

// ---------------- K2 v10b
#define BM 128
#define NT 128                  // K-steps of 64 per block (K-half = 8192)
#define A_ST 72                 // hw stride: 64 data + 8 pad (144 B, 16B-aligned b128)
#define B_ST 72

// issue data(STEP_) into register set SET (8 x 16B loads; SET is literal 0/1)
#define ISSUE(SET, STEP_)                                                     \
  do {                                                                        \
    const int4*  ap_ = pa4 + (size_t)(STEP_) * 16;                            \
    const uint4* bp_ = pb4 + (size_t)(STEP_) * 2048;                          \
    aR[SET][0] = ap_[0]; aR[SET][1] = ap_[1];                                 \
    aR[SET][2] = ap_[2]; aR[SET][3] = ap_[3];                                 \
    bR[SET][0] = bp_[0]; bR[SET][1] = bp_[1];                                 \
    bR[SET][2] = bp_[2]; bR[SET][3] = bp_[3];                                 \
  } while (0)

// convert+write register set SET into LDS buffer BUF (both literal)
#define STAGE(SET, BUF)                                                       \
  do {                                                                        \
    degp += aR[SET][0].x + aR[SET][0].y + aR[SET][0].z + aR[SET][0].w         \
          + aR[SET][1].x + aR[SET][1].y + aR[SET][1].z + aR[SET][1].w         \
          + aR[SET][2].x + aR[SET][2].y + aR[SET][2].z + aR[SET][2].w         \
          + aR[SET][3].x + aR[SET][3].y + aR[SET][3].z + aR[SET][3].w;        \
    uint4 w0_, w1_;                                                           \
    w0_.x = (uint32_t)(aR[SET][0].x | (aR[SET][0].y << 16)) * 0x3F80u;        \
    w0_.y = (uint32_t)(aR[SET][0].z | (aR[SET][0].w << 16)) * 0x3F80u;        \
    w0_.z = (uint32_t)(aR[SET][1].x | (aR[SET][1].y << 16)) * 0x3F80u;        \
    w0_.w = (uint32_t)(aR[SET][1].z | (aR[SET][1].w << 16)) * 0x3F80u;        \
    w1_.x = (uint32_t)(aR[SET][2].x | (aR[SET][2].y << 16)) * 0x3F80u;        \
    w1_.y = (uint32_t)(aR[SET][2].z | (aR[SET][2].w << 16)) * 0x3F80u;        \
    w1_.z = (uint32_t)(aR[SET][3].x | (aR[SET][3].y << 16)) * 0x3F80u;        \
    w1_.w = (uint32_t)(aR[SET][3].z | (aR[SET][3].w << 16)) * 0x3F80u;        \
    *(uint4*)&As[BUF][a_wr]      = w0_;                                       \
    *(uint4*)&As[BUF][a_wr + 8]  = w1_;                                       \
    *(uint4*)&Bs[BUF][b_wr]      = bR[SET][0];                                \
    *(uint4*)&Bs[BUF][b_wr + 8]  = bR[SET][1];                                \
    *(uint4*)&Bs[BUF][b_wr + 16] = bR[SET][2];                                \
    *(uint4*)&Bs[BUF][b_wr + 24] = bR[SET][3];                                \
  } while (0)

// 32 MFMA on buffer BUF (compile-time BUF); kh-serial keeps frag VGPRs at 32
#define COMPUTE(BUF)                                                          \
  do {                                                                        \
    _Pragma("unroll") for (int kh = 0; kh < 2; ++kh) {                        \
      bf16x8 af[4], bfr[4];                                                   \
      _Pragma("unroll") for (int fr = 0; fr < 4; ++fr)                        \
        af[fr] = *(const bf16x8*)&As[BUF][(wr * 64 + fr * 16 + l15) * A_ST +  \
                                          kh * 32 + quad * 8];                \
      _Pragma("unroll") for (int fc = 0; fc < 4; ++fc)                        \
        bfr[fc] = *(const bf16x8*)&Bs[BUF][(wc * 64 + fc * 16 + l15) * B_ST + \
                                           kh * 32 + quad * 8];               \
      _Pragma("unroll") for (int fr = 0; fr < 4; ++fr)                        \
        _Pragma("unroll") for (int fc = 0; fc < 4; ++fc)                      \
          acc[fr][fc] = __builtin_amdgcn_mfma_f32_16x16x32_bf16(              \
              af[fr], bfr[fc], acc[fr][fc], 0, 0, 0);                         \
    }                                                                         \
  } while (0)

__global__ __launch_bounds__(512) void k_big_gemm(const int* __restrict__ adj,
                                                  const uint16_t* __restrict__ yTt,
                                                  float* __restrict__ part,
                                                  int* __restrict__ degw) {
    __shared__ __align__(16) uint16_t As[2][BM * A_ST];    // 36.9 KB
    __shared__ __align__(16) uint16_t Bs[2][256 * B_ST];   // 73.7 KB

    const int t = threadIdx.x;
    const int m0 = blockIdx.x * BM;
    const int ky = blockIdx.y;                 // k-half
    const int lane = t & 63, w = t >> 6;
    const int wr = w >> 2, wc = w & 3;         // 2x4 waves, wave tile 64x64
    const int l15 = lane & 15, quad = lane >> 4;

    f32x4 acc[4][4] = {};

    // A: 128 rows x 64 ints / step; thread -> row t>>2, 16-int chunk t&3 (64B contig)
    const int a_row = t >> 2, a_c = t & 3;
    const int4* pa4 = (const int4*)(adj + (size_t)(m0 + a_row) * 16384 + ky * 8192) + a_c * 4;
    const int a_wr = a_row * A_ST + a_c * 16;  // hw

    // B: step tt = yTt tiles (ky*256 + 2tt, +1); thread -> tile-half t>>8, col t&255 (64B contig)
    const int b_kt = t >> 8, b_n = t & 255;
    const uint4* pb4 = (const uint4*)(yTt + ((size_t)ky * 256 + b_kt) * 8192 + b_n * 32);
    const int b_wr = b_n * B_ST + b_kt * 32;   // hw

    int4  aR[2][4];
    uint4 bR[2][4];
    int degp = 0;

    // ---- prologue: data(0) -> set0, data(1) -> set1; stage 0 -> buf0
    ISSUE(0, 0);
    asm volatile("" ::: "memory");             // keep set0's 8 loads oldest
    ISSUE(1, 1);
    asm volatile("s_waitcnt vmcnt(8)" ::: "memory");   // set0 landed, set1 in flight
    STAGE(0, 0);
    asm volatile("s_waitcnt lgkmcnt(0)\n\ts_barrier" ::: "memory");

    // ---- main loop: pairs of steps; data(k) lives in set k&1 / buf k&1
    for (int tt = 0; tt < NT - 2; tt += 2) {
        ISSUE(0, tt + 2);                       // 16 outstanding
        asm volatile("s_waitcnt vmcnt(8)" ::: "memory");  // oldest 8 = set1(tt+1)
        STAGE(1, 1);
        __builtin_amdgcn_s_setprio(1);
        COMPUTE(0);
        __builtin_amdgcn_s_setprio(0);
        asm volatile("s_waitcnt lgkmcnt(0)\n\ts_barrier" ::: "memory");

        ISSUE(1, tt + 3);
        asm volatile("s_waitcnt vmcnt(8)" ::: "memory");  // oldest 8 = set0(tt+2)
        STAGE(0, 0);
        __builtin_amdgcn_s_setprio(1);
        COMPUTE(1);
        __builtin_amdgcn_s_setprio(0);
        asm volatile("s_waitcnt lgkmcnt(0)\n\ts_barrier" ::: "memory");
    }
    // tail: data(NT-1) in set1 still in flight
    asm volatile("s_waitcnt vmcnt(0)" ::: "memory");
    STAGE(1, 1);
    __builtin_amdgcn_s_setprio(1);
    COMPUTE(0);
    __builtin_amdgcn_s_setprio(0);
    asm volatile("s_waitcnt lgkmcnt(0)\n\ts_barrier" ::: "memory");
    COMPUTE(1);

    // partial deg: row a_row owned by 4 consecutive lanes (t&3)
    degp += __shfl_down(degp, 2);
    degp += __shfl_down(degp, 1);
    if ((t & 3) == 0) degw[ky * 16384 + m0 + a_row] = degp;

    // partial C (C/D layout: col=lane&15, row=quad*4+reg)
    float* pc = part + (size_t)ky * 16384 * 256 + (size_t)m0 * 256;
#pragma unroll
    for (int fr = 0; fr < 4; ++fr) {
#pragma unroll
        for (int r = 0; r < 4; ++r) {
            int m_l = wr * 64 + fr * 16 + quad * 4 + r;
            size_t mrow = (size_t)m_l * 256;
#pragma unroll
            for (int fc = 0; fc < 4; ++fc) {
                int n_g = wc * 64 + fc * 16 + l15;
                pc[mrow + n_g] = acc[fr][fc][r];
            }
        }
    }
}

// ---------------- K3: out = (p0+p1)/(d0+d1) + z
__global__ __launch_bounds__(256) void k_reduce(const float* __restrict__ part,
                                                const int* __restrict__ degw,
                                                const float* __restrict__ z,
                                                float* __restrict__ out) {
    int i4 = blockIdx.x * 256 + threadIdx.x;       // float4 index, 64 per row
    int m = i4 >> 6;
    float4 p0 = ((const float4*)part)[i4];
    float4 p1 = ((const float4*)part)[i4 + 16384 * 64];
    float4 zz = ((const float4*)z)[i4];
    float inv = 1.0f / (float)(degw[m] + degw[16384 + m]);
    float4 o;
    o.x = (p0.x + p1.x) * inv + zz.x;
    o.y = (p0.y + p1.y) * inv + zz.y;
    o.z = (p0.z + p1.z) * inv + zz.z;
    o.w = (p0.w + p1.w) * inv + zz.w;
    ((float4*)out)[i4] = o;
}

extern "C" void kernel_launch(void* const* d_in, const int* in_sizes, int n_in,
                              void* d_out, int out_size, void* d_ws, size_t ws_size,
                              hipStream_t stream) {
    const float* x      = (const float*)d_in[0];
    const int*   adj    = (const int*)d_in[1];
    const float* weight = (const float*)d_in[2];
    const float* bias   = (const float*)d_in[3];
    float* out = (float*)d_out;

    // ws: WT 256KB | yTt 8MB | z 16MB | part 32MB | degw 128KB
    char* wsb = (char*)d_ws;
    uint16_t* wt   = (uint16_t*)(wsb);
    uint16_t* yTt  = (uint16_t*)(wsb + 262144);
    float*    z    = (float*)(wsb + 262144 + 8388608);
    float*    partb= (float*)(wsb + 262144 + 8388608 + 16777216);
    int*      degw = (int*)(wsb + 262144 + 8388608 + 16777216 + 33554432);

    k_transpose_w<<<512, 256, 0, stream>>>(weight, wt);
    k_small_gemm<<<dim3(4, 128), 256, 0, stream>>>(x, wt, bias, yTt, z);
    k_big_gemm<<<dim3(128, 2), 512, 0, stream>>>(adj, yTt, partb, degw);
    k_reduce<<<4096, 256, 0, stream>>>(partb, degw, z, out);
}

// Round 3
// 1494.308 us; speedup vs baseline: 1.1134x; 1.1134x over previous
//
#include <hip/hip_runtime.h>
#include <hip/hip_bf16.h>
#include <stdint.h>

// GraphSAGE layer, N=16384, F_IN=F_OUT=256.
// out = (adj@ (x@W1))/deg + x@W2 + bias
//   K0: WT[n][k] (bf16)  = transpose of [W1|W2]
//   K1: yTt[j/32][n][32] (bf16, K-TILED) = (x@W1)^T ; z[m][n] = x@W2 + bias
//   K2 v11: BM=64, BK=32, split-K 2, 8 waves of 32x64, TRI-buffered A-only
//          LDS (13.8 KB; B staging DELETED — B fragments load DIRECT from
//          L2-resident yTt as perfectly-coalesced 1KB wave loads, double-
//          buffered in registers). A all-register staging with 3-step
//          rotation slack (compiler-placed vmcnt), raw s_barrier with
//          lgkmcnt(0) only. XCD swizzle partitions ky per XCD half so each
//          XCD's B working set = 4 MB = its L2.
//   K3: out = (p0+p1)/(d0+d1) + z

typedef short bf16x8 __attribute__((ext_vector_type(8)));
typedef float f32x4  __attribute__((ext_vector_type(4)));

__device__ __forceinline__ uint32_t pack_bf16_rne(float lo, float hi) {
    uint32_t ul = __float_as_uint(lo);
    uint32_t uh = __float_as_uint(hi);
    ul = (ul + 0x7fffu + ((ul >> 16) & 1u)) >> 16;
    uh = (uh + 0x7fffu + ((uh >> 16) & 1u)) >> 16;
    return ul | (uh << 16);
}

// ---------------- K0: transpose weight [512,256] f32 -> WT [512(n)][256(k)] bf16
__global__ __launch_bounds__(256) void k_transpose_w(const float* __restrict__ w,
                                                     uint16_t* __restrict__ wt) {
    int idx = blockIdx.x * 256 + threadIdx.x;   // 0..131071
    int n = idx >> 8;
    int k = idx & 255;
    int row = (n < 256) ? k : (256 + k);
    int col = (n < 256) ? n : (n - 256);
    uint32_t u = __float_as_uint(w[row * 256 + col]);
    u = (u + 0x7fffu + ((u >> 16) & 1u)) >> 16;
    wt[idx] = (uint16_t)u;
}

// ---------------- K1: small GEMM  [16384,256] @ [256,512]
// -> yTt (K-tiled transpose, cols 0..255) / z (cols 256..511)
__global__ __launch_bounds__(256) void k_small_gemm(const float* __restrict__ x,
                                                    const uint16_t* __restrict__ wt,
                                                    const float* __restrict__ bias,
                                                    uint16_t* __restrict__ yTt,
                                                    float* __restrict__ z) {
    __shared__ uint16_t As[128 * 32];  // [m][k] bf16
    __shared__ uint16_t Bs[128 * 32];  // [n][k] bf16

    const int t  = threadIdx.x;
    const int ct = blockIdx.x;        // 0..3
    const int rt = blockIdx.y;        // 0..127
    const int m0 = rt * 128;
    const int n0 = ct * 128;

    const int lane = t & 63, w = t >> 6;
    const int wr = w >> 1, wc = w & 1;
    const int l15 = lane & 15, quad = lane >> 4;

    f32x4 acc[4][4] = {};

    float4 a_reg[4];
    uint4  b_reg[2];

#pragma unroll
    for (int i = 0; i < 4; ++i) {
        int f4 = t + 256 * i, row = f4 >> 3, c4 = f4 & 7;
        a_reg[i] = *(const float4*)(x + (m0 + row) * 256 + c4 * 4);
    }
#pragma unroll
    for (int i = 0; i < 2; ++i) {
        int u4 = t + 256 * i, n_l = u4 >> 2, part = u4 & 3;
        b_reg[i] = *(const uint4*)(wt + (n0 + n_l) * 256 + part * 8);
    }

    for (int kk = 0; kk < 8; ++kk) {
        __syncthreads();
#pragma unroll
        for (int i = 0; i < 4; ++i) {
            int f4 = t + 256 * i, row = f4 >> 3, c4 = f4 & 7;
            uint2 p;
            p.x = pack_bf16_rne(a_reg[i].x, a_reg[i].y);
            p.y = pack_bf16_rne(a_reg[i].z, a_reg[i].w);
            *(uint2*)(As + row * 32 + c4 * 4) = p;
        }
#pragma unroll
        for (int i = 0; i < 2; ++i) {
            int u4 = t + 256 * i, n_l = u4 >> 2, part = u4 & 3;
            *(uint4*)(Bs + n_l * 32 + part * 8) = b_reg[i];
        }
        if (kk < 7) {
            int k0 = (kk + 1) * 32;
#pragma unroll
            for (int i = 0; i < 4; ++i) {
                int f4 = t + 256 * i, row = f4 >> 3, c4 = f4 & 7;
                a_reg[i] = *(const float4*)(x + (m0 + row) * 256 + k0 + c4 * 4);
            }
#pragma unroll
            for (int i = 0; i < 2; ++i) {
                int u4 = t + 256 * i, n_l = u4 >> 2, part = u4 & 3;
                b_reg[i] = *(const uint4*)(wt + (n0 + n_l) * 256 + k0 + part * 8);
            }
        }
        __syncthreads();

        bf16x8 a_frag[4], b_frag[4];
#pragma unroll
        for (int fr = 0; fr < 4; ++fr)
            a_frag[fr] = *(const bf16x8*)(As + (wr * 64 + fr * 16 + l15) * 32 + quad * 8);
#pragma unroll
        for (int fc = 0; fc < 4; ++fc)
            b_frag[fc] = *(const bf16x8*)(Bs + (wc * 64 + fc * 16 + l15) * 32 + quad * 8);
#pragma unroll
        for (int fr = 0; fr < 4; ++fr)
#pragma unroll
            for (int fc = 0; fc < 4; ++fc)
                acc[fr][fc] = __builtin_amdgcn_mfma_f32_16x16x32_bf16(
                    a_frag[fr], b_frag[fc], acc[fr][fc], 0, 0, 0);
    }

    if (ct < 2) {
        // y^T K-tiled: yTt[(m>>5)][n][32] + (m&31); lane's 4 regs = 4
        // consecutive m inside one 32-tile (m_base%32 <= 28) -> one uint2
#pragma unroll
        for (int fr = 0; fr < 4; ++fr) {
            int m_base = m0 + wr * 64 + fr * 16 + quad * 4;
#pragma unroll
            for (int fc = 0; fc < 4; ++fc) {
                int n_g = n0 + wc * 64 + fc * 16 + l15;   // 0..255
                uint2 pp;
                pp.x = pack_bf16_rne(acc[fr][fc][0], acc[fr][fc][1]);
                pp.y = pack_bf16_rne(acc[fr][fc][2], acc[fr][fc][3]);
                *(uint2*)(yTt + (size_t)(m_base >> 5) * 8192 + n_g * 32 + (m_base & 31)) = pp;
            }
        }
    } else {
#pragma unroll
        for (int fr = 0; fr < 4; ++fr) {
            int m_base = m0 + wr * 64 + fr * 16 + quad * 4;
#pragma unroll
            for (int fc = 0; fc < 4; ++fc) {
                int n_g = (n0 - 256) + wc * 64 + fc * 16 + l15;  // 0..255
                float bv = bias[n_g];
#pragma unroll
                for (int r = 0; r < 4; ++r)
                    z[(size_t)(m_base + r) * 256 + n_g] = acc[fr][fc][r] + bv;
            }
        }
    }
}

// ---------------- K2 v11
#define A_STRIDE 36                 // 64 rows x 36 hw (32 data + 4 pad) — bank-balanced
#define A_SZ (64 * A_STRIDE)        // 2304 hw = 4.6 KB per buffer
#define KITER 256

// One step. ARD/AWR: compile-time A-LDS buffer ids. KK: step index.
// B for step KK is in bC[4] (registers); prefetch bN = B(KK+1) direct
// from yTt (L2-resident, perfectly coalesced 1KB/wave loads).
#define STEP(ARD, AWR, KK)                                                      \
  do {                                                                          \
    if ((KK) < KITER - 1) {  /* B(KK+1) -> regs */                              \
      _Pragma("unroll") for (int fc = 0; fc < 4; ++fc)                          \
        bN[fc] = *(const bf16x8*)(pB + fc * 512);                               \
      pB += 8192;                                                               \
    }                                                                           \
    if ((KK) < KITER - 3) {  /* A(KK+3) regs */                                 \
      aN = pa4[0]; pa4 += 8;                                                    \
    }                                                                           \
    if ((KK) < KITER - 1) {  /* stage A(KK+1) -> LDS */                         \
      degp += aQ0.x + aQ0.y + aQ0.z + aQ0.w;                                    \
      uint2 pv;                                                                 \
      pv.x = (uint32_t)(aQ0.x | (aQ0.y << 16)) * 0x3F80u;                       \
      pv.y = (uint32_t)(aQ0.z | (aQ0.w << 16)) * 0x3F80u;                       \
      *(uint2*)&As##AWR[a_lds] = pv;                                            \
    }                                                                           \
    {                                                                           \
      bf16x8 af[2];                                                             \
      _Pragma("unroll") for (int fr = 0; fr < 2; ++fr) {                        \
        int row = wr * 32 + fr * 16 + l15;                                      \
        af[fr] = *(const bf16x8*)(As##ARD + row * A_STRIDE + quad * 8);         \
      }                                                                         \
      _Pragma("unroll") for (int fr = 0; fr < 2; ++fr)                          \
        _Pragma("unroll") for (int fc = 0; fc < 4; ++fc)                        \
          acc[fr][fc] = __builtin_amdgcn_mfma_f32_16x16x32_bf16(                \
              af[fr], bC[fc], acc[fr][fc], 0, 0, 0);                            \
    }                                                                           \
    aQ0 = aQ1; aQ1 = aQ2; aQ2 = aN;                                             \
    _Pragma("unroll") for (int fc = 0; fc < 4; ++fc) bC[fc] = bN[fc];           \
    asm volatile("s_waitcnt lgkmcnt(0)\n\ts_barrier" ::: "memory");             \
  } while (0)

__global__ __launch_bounds__(512, 4) void k_big_gemm(const int* __restrict__ adj,
                                                     const uint16_t* __restrict__ yTt,
                                                     float* __restrict__ part,
                                                     int* __restrict__ degw) {
    __shared__ uint16_t As0[A_SZ], As1[A_SZ], As2[A_SZ];   // 13.8 KB total

    const int t = threadIdx.x;
    // XCD swizzle: round-robin dispatch => xcd = linear_id & 7 [m09].
    // Partition ky by XCD half: XCD 0-3 -> ky 0, XCD 4-7 -> ky 1, so each
    // XCD's B (yTt half, 4 MB) fits its private L2. Bijective remap.
    const int id   = blockIdx.x + (int)gridDim.x * blockIdx.y;  // 0..511
    const int xcd  = id & 7, slot = id >> 3;                    // slot 0..63
    const int ky   = xcd >> 2;
    const int m0   = ((xcd & 3) * 64 + slot) * 64;
    const int lane = t & 63, w = t >> 6;
    const int wr = w >> 2, wc = w & 3;             // wave: 2 row frags, 4 col frags
    const int l15 = lane & 15, quad = lane >> 4;

    f32x4 acc[2][4] = {};

    // A: 64 rows x 32 ints / stage = 512 int4, one per thread
    const int a_n = t >> 3, a_c4 = t & 7;
    const int4* pa4 = (const int4*)(adj + (size_t)(m0 + a_n) * 16384 + ky * 8192) + a_c4;
    const int a_lds = a_n * A_STRIDE + a_c4 * 4;

    // B: fragment-direct from yTt. Lane addr for step kk (tile kt=ky*256+kk):
    //   yTt + kt*8192 + (wc*64 + fc*16 + l15)*32 + quad*8  — 16B/lane,
    //   64 lanes cover a contiguous 1KB per fragment load. +8192 per step.
    const uint16_t* pB = yTt + (size_t)(ky * 256) * 8192
                       + (size_t)(wc * 64 + l15) * 32 + quad * 8;

    bf16x8 bC[4], bN[4];
    int4 aQ0, aQ1, aQ2, aN;
    int degp;

    // ---- prologue: A(0..2) regs, stage A(0) -> buf0; B(0) -> bC
    int4 a0 = pa4[0];
    aQ0 = pa4[8];                 // A(1)
    aQ1 = pa4[16];                // A(2)
    aQ2 = aQ1;                    // A(3) loaded in step 0
    aN  = aQ1;
    pa4 += 24;
#pragma unroll
    for (int fc = 0; fc < 4; ++fc) bN[fc] = *(const bf16x8*)(pB + fc * 512);
    pB += 8192;
#pragma unroll
    for (int fc = 0; fc < 4; ++fc) bC[fc] = bN[fc];

    degp = a0.x + a0.y + a0.z + a0.w;
    {
        uint2 pv;
        pv.x = (uint32_t)(a0.x | (a0.y << 16)) * 0x3F80u;
        pv.y = (uint32_t)(a0.z | (a0.w << 16)) * 0x3F80u;
        *(uint2*)&As0[a_lds] = pv;
    }
    asm volatile("s_waitcnt lgkmcnt(0)\n\ts_barrier" ::: "memory");

    // ---- main loop: 84 triples = steps 0..251 (all guards true), tail 252..255
    for (int kk = 0; kk < KITER - 4; kk += 3) {
        STEP(0, 1, kk);
        STEP(1, 2, kk + 1);
        STEP(2, 0, kk + 2);
    }
    STEP(0, 1, 252);
    STEP(1, 2, 253);
    STEP(2, 0, 254);
    STEP(0, 1, 255);

    // partial deg: row a_n owned by 8 consecutive lanes
    degp += __shfl_down(degp, 4);
    degp += __shfl_down(degp, 2);
    degp += __shfl_down(degp, 1);
    if ((t & 7) == 0) degw[ky * 16384 + m0 + a_n] = degp;

    // partial C (C/D layout: col=lane&15, row=quad*4+reg)
    float* pc = part + (size_t)ky * 16384 * 256;
#pragma unroll
    for (int fr = 0; fr < 2; ++fr) {
#pragma unroll
        for (int r = 0; r < 4; ++r) {
            int m_l = wr * 32 + fr * 16 + quad * 4 + r;
            size_t mrow = (size_t)(m0 + m_l) * 256;
#pragma unroll
            for (int fc = 0; fc < 4; ++fc) {
                int n_g = wc * 64 + fc * 16 + l15;
                pc[mrow + n_g] = acc[fr][fc][r];
            }
        }
    }
}

// ---------------- K3: out = (p0+p1)/(d0+d1) + z
__global__ __launch_bounds__(256) void k_reduce(const float* __restrict__ part,
                                                const int* __restrict__ degw,
                                                const float* __restrict__ z,
                                                float* __restrict__ out) {
    int i4 = blockIdx.x * 256 + threadIdx.x;       // float4 index, 64 per row
    int m = i4 >> 6;
    float4 p0 = ((const float4*)part)[i4];
    float4 p1 = ((const float4*)part)[i4 + 16384 * 64];
    float4 zz = ((const float4*)z)[i4];
    float inv = 1.0f / (float)(degw[m] + degw[16384 + m]);
    float4 o;
    o.x = (p0.x + p1.x) * inv + zz.x;
    o.y = (p0.y + p1.y) * inv + zz.y;
    o.z = (p0.z + p1.z) * inv + zz.z;
    o.w = (p0.w + p1.w) * inv + zz.w;
    ((float4*)out)[i4] = o;
}

extern "C" void kernel_launch(void* const* d_in, const int* in_sizes, int n_in,
                              void* d_out, int out_size, void* d_ws, size_t ws_size,
                              hipStream_t stream) {
    const float* x      = (const float*)d_in[0];
    const int*   adj    = (const int*)d_in[1];
    const float* weight = (const float*)d_in[2];
    const float* bias   = (const float*)d_in[3];
    float* out = (float*)d_out;

    // ws: WT 256KB | yTt 8MB | z 16MB | part 32MB | degw 128KB
    char* wsb = (char*)d_ws;
    uint16_t* wt   = (uint16_t*)(wsb);
    uint16_t* yTt  = (uint16_t*)(wsb + 262144);
    float*    z    = (float*)(wsb + 262144 + 8388608);
    float*    partb= (float*)(wsb + 262144 + 8388608 + 16777216);
    int*      degw = (int*)(wsb + 262144 + 8388608 + 16777216 + 33554432);

    k_transpose_w<<<512, 256, 0, stream>>>(weight, wt);
    k_small_gemm<<<dim3(4, 128), 256, 0, stream>>>(x, wt, bias, yTt, z);
    k_big_gemm<<<dim3(256, 2), 512, 0, stream>>>(adj, yTt, partb, degw);
    k_reduce<<<4096, 256, 0, stream>>>(partb, degw, z, out);
}

// Round 4
// 1425.163 us; speedup vs baseline: 1.1674x; 1.0485x over previous
//
#include <hip/hip_runtime.h>
#include <hip/hip_bf16.h>
#include <stdint.h>

// GraphSAGE layer, N=16384, F_IN=F_OUT=256.
// out = (adj@ (x@W1))/deg + x@W2 + bias
//   K0: WT[n][k] (bf16)  = transpose of [W1|W2]
//   K1: yTt[j/32][n][32] (bf16, K-TILED) = (x@W1)^T ; z[m][n] = x@W2 + bias
//   K2 v12: v9 structure (split-K 2, 8 waves of 32x64, BK=32, TRI-buffered
//          LDS for A and B, all-register staging, raw s_barrier w/ lgkmcnt(0)
//          only) with three L2-protection changes:
//            - adj loads NON-TEMPORAL (read-once stream; stop evicting yTt)
//            - part stores NON-TEMPORAL (write-once stream)
//            - ky partitioned per XCD half (each XCD's yTt slice = 4MB = L2)
//          plus a provably-aligned explicit A prefetch queue (v9's rotation
//          relied on an uninitialized slot).
//   K3: out = (p0+p1)/(d0+d1) + z

typedef short bf16x8 __attribute__((ext_vector_type(8)));
typedef float f32x4  __attribute__((ext_vector_type(4)));
typedef int   i32x4  __attribute__((ext_vector_type(4)));

__device__ __forceinline__ uint32_t pack_bf16_rne(float lo, float hi) {
    uint32_t ul = __float_as_uint(lo);
    uint32_t uh = __float_as_uint(hi);
    ul = (ul + 0x7fffu + ((ul >> 16) & 1u)) >> 16;
    uh = (uh + 0x7fffu + ((uh >> 16) & 1u)) >> 16;
    return ul | (uh << 16);
}

// ---------------- K0: transpose weight [512,256] f32 -> WT [512(n)][256(k)] bf16
__global__ __launch_bounds__(256) void k_transpose_w(const float* __restrict__ w,
                                                     uint16_t* __restrict__ wt) {
    int idx = blockIdx.x * 256 + threadIdx.x;   // 0..131071
    int n = idx >> 8;
    int k = idx & 255;
    int row = (n < 256) ? k : (256 + k);
    int col = (n < 256) ? n : (n - 256);
    uint32_t u = __float_as_uint(w[row * 256 + col]);
    u = (u + 0x7fffu + ((u >> 16) & 1u)) >> 16;
    wt[idx] = (uint16_t)u;
}

// ---------------- K1: small GEMM  [16384,256] @ [256,512]
// -> yTt (K-tiled transpose, cols 0..255) / z (cols 256..511)
__global__ __launch_bounds__(256) void k_small_gemm(const float* __restrict__ x,
                                                    const uint16_t* __restrict__ wt,
                                                    const float* __restrict__ bias,
                                                    uint16_t* __restrict__ yTt,
                                                    float* __restrict__ z) {
    __shared__ uint16_t As[128 * 32];  // [m][k] bf16
    __shared__ uint16_t Bs[128 * 32];  // [n][k] bf16

    const int t  = threadIdx.x;
    const int ct = blockIdx.x;        // 0..3
    const int rt = blockIdx.y;        // 0..127
    const int m0 = rt * 128;
    const int n0 = ct * 128;

    const int lane = t & 63, w = t >> 6;
    const int wr = w >> 1, wc = w & 1;
    const int l15 = lane & 15, quad = lane >> 4;

    f32x4 acc[4][4] = {};

    float4 a_reg[4];
    uint4  b_reg[2];

#pragma unroll
    for (int i = 0; i < 4; ++i) {
        int f4 = t + 256 * i, row = f4 >> 3, c4 = f4 & 7;
        a_reg[i] = *(const float4*)(x + (m0 + row) * 256 + c4 * 4);
    }
#pragma unroll
    for (int i = 0; i < 2; ++i) {
        int u4 = t + 256 * i, n_l = u4 >> 2, part = u4 & 3;
        b_reg[i] = *(const uint4*)(wt + (n0 + n_l) * 256 + part * 8);
    }

    for (int kk = 0; kk < 8; ++kk) {
        __syncthreads();
#pragma unroll
        for (int i = 0; i < 4; ++i) {
            int f4 = t + 256 * i, row = f4 >> 3, c4 = f4 & 7;
            uint2 p;
            p.x = pack_bf16_rne(a_reg[i].x, a_reg[i].y);
            p.y = pack_bf16_rne(a_reg[i].z, a_reg[i].w);
            *(uint2*)(As + row * 32 + c4 * 4) = p;
        }
#pragma unroll
        for (int i = 0; i < 2; ++i) {
            int u4 = t + 256 * i, n_l = u4 >> 2, part = u4 & 3;
            *(uint4*)(Bs + n_l * 32 + part * 8) = b_reg[i];
        }
        if (kk < 7) {
            int k0 = (kk + 1) * 32;
#pragma unroll
            for (int i = 0; i < 4; ++i) {
                int f4 = t + 256 * i, row = f4 >> 3, c4 = f4 & 7;
                a_reg[i] = *(const float4*)(x + (m0 + row) * 256 + k0 + c4 * 4);
            }
#pragma unroll
            for (int i = 0; i < 2; ++i) {
                int u4 = t + 256 * i, n_l = u4 >> 2, part = u4 & 3;
                b_reg[i] = *(const uint4*)(wt + (n0 + n_l) * 256 + k0 + part * 8);
            }
        }
        __syncthreads();

        bf16x8 a_frag[4], b_frag[4];
#pragma unroll
        for (int fr = 0; fr < 4; ++fr)
            a_frag[fr] = *(const bf16x8*)(As + (wr * 64 + fr * 16 + l15) * 32 + quad * 8);
#pragma unroll
        for (int fc = 0; fc < 4; ++fc)
            b_frag[fc] = *(const bf16x8*)(Bs + (wc * 64 + fc * 16 + l15) * 32 + quad * 8);
#pragma unroll
        for (int fr = 0; fr < 4; ++fr)
#pragma unroll
            for (int fc = 0; fc < 4; ++fc)
                acc[fr][fc] = __builtin_amdgcn_mfma_f32_16x16x32_bf16(
                    a_frag[fr], b_frag[fc], acc[fr][fc], 0, 0, 0);
    }

    if (ct < 2) {
        // y^T K-tiled: yTt[(m>>5)][n][32] + (m&31); lane's 4 regs = 4
        // consecutive m inside one 32-tile (m_base%32 <= 28) -> one uint2
#pragma unroll
        for (int fr = 0; fr < 4; ++fr) {
            int m_base = m0 + wr * 64 + fr * 16 + quad * 4;
#pragma unroll
            for (int fc = 0; fc < 4; ++fc) {
                int n_g = n0 + wc * 64 + fc * 16 + l15;   // 0..255
                uint2 pp;
                pp.x = pack_bf16_rne(acc[fr][fc][0], acc[fr][fc][1]);
                pp.y = pack_bf16_rne(acc[fr][fc][2], acc[fr][fc][3]);
                *(uint2*)(yTt + (size_t)(m_base >> 5) * 8192 + n_g * 32 + (m_base & 31)) = pp;
            }
        }
    } else {
#pragma unroll
        for (int fr = 0; fr < 4; ++fr) {
            int m_base = m0 + wr * 64 + fr * 16 + quad * 4;
#pragma unroll
            for (int fc = 0; fc < 4; ++fc) {
                int n_g = (n0 - 256) + wc * 64 + fc * 16 + l15;  // 0..255
                float bv = bias[n_g];
#pragma unroll
                for (int r = 0; r < 4; ++r)
                    z[(size_t)(m_base + r) * 256 + n_g] = acc[fr][fc][r] + bv;
            }
        }
    }
}

// ---------------- K2 v12
#define A_STRIDE 36                 // 64 rows x 36 hw (32 data + 4 pad) — bank-balanced
#define B_STRIDE 36                 // 256 rows x 36 hw
#define A_SZ (64 * A_STRIDE)        // 2304 hw = 4.5 KB
#define B_SZ (256 * B_STRIDE)       // 9216 hw = 18 KB
#define KITER 256

// One step. RD/WR: compile-time LDS buffer ids. KK: step index (runtime ok).
// A queue invariant at entry of step KK: q1=A(KK+1), q2=A(KK+2), q3=A(KK+3).
// B invariant: bC = B(KK+1) (bN = B(KK+2) loaded in-step).
#define STEP(ARD, BRD, AWR, BWR, KK)                                            \
  do {                                                                          \
    if ((KK) < KITER - 2) {  /* B(KK+2) regs */                                 \
      bN0 = *(const uint4*)(pB);                                                \
      bN1 = *(const uint4*)(pB + 4096);                                         \
      pB += 8192;                                                               \
    }                                                                           \
    if ((KK) < KITER - 4) {  /* A(KK+4) regs, non-temporal */                   \
      aN = __builtin_nontemporal_load(pa4); pa4 += 8;                           \
    }                                                                           \
    if ((KK) < KITER - 1) {  /* stage KK+1 -> LDS */                            \
      degp += q1.x + q1.y + q1.z + q1.w;                                        \
      uint2 pv;                                                                 \
      pv.x = (uint32_t)(q1.x | (q1.y << 16)) * 0x3F80u;                         \
      pv.y = (uint32_t)(q1.z | (q1.w << 16)) * 0x3F80u;                         \
      *(uint2*)&As##AWR[a_lds] = pv;                                            \
      *(uint4*)&Bs##BWR[b_lds0] = bC0;                                          \
      *(uint4*)&Bs##BWR[b_lds1] = bC1;                                          \
    }                                                                           \
    {                                                                           \
      bf16x8 af[2], bfr[4];                                                     \
      _Pragma("unroll") for (int fr = 0; fr < 2; ++fr) {                        \
        int row = wr * 32 + fr * 16 + l15;                                      \
        af[fr] = *(const bf16x8*)(As##ARD + row * A_STRIDE + quad * 8);         \
      }                                                                         \
      _Pragma("unroll") for (int fc = 0; fc < 4; ++fc) {                        \
        int n = wc * 64 + fc * 16 + l15;                                        \
        bfr[fc] = *(const bf16x8*)(Bs##BRD + n * B_STRIDE + quad * 8);          \
      }                                                                         \
      _Pragma("unroll") for (int fr = 0; fr < 2; ++fr)                          \
        _Pragma("unroll") for (int fc = 0; fc < 4; ++fc)                        \
          acc[fr][fc] = __builtin_amdgcn_mfma_f32_16x16x32_bf16(                \
              af[fr], bfr[fc], acc[fr][fc], 0, 0, 0);                           \
    }                                                                           \
    q1 = q2; q2 = q3; q3 = aN;                                                  \
    bC0 = bN0; bC1 = bN1;                                                       \
    asm volatile("s_waitcnt lgkmcnt(0)\n\ts_barrier" ::: "memory");             \
  } while (0)

__global__ __launch_bounds__(512, 4) void k_big_gemm(const int* __restrict__ adj,
                                                     const uint16_t* __restrict__ yTt,
                                                     float* __restrict__ part,
                                                     int* __restrict__ degw) {
    __shared__ uint16_t As0[A_SZ], As1[A_SZ], As2[A_SZ];   // 13.5 KB
    __shared__ uint16_t Bs0[B_SZ], Bs1[B_SZ], Bs2[B_SZ];   // 54 KB

    const int t = threadIdx.x;
    // XCD swizzle: round-robin dispatch => xcd = linear_id & 7 [m09].
    // Partition ky by XCD half so each XCD's yTt slice (4 MB) fits its L2.
    const int id   = blockIdx.x + (int)gridDim.x * blockIdx.y;  // 0..511
    const int xcd  = id & 7, slot = id >> 3;                    // slot 0..63
    const int ky   = xcd >> 2;
    const int m0   = ((xcd & 3) * 64 + slot) * 64;
    const int lane = t & 63, w = t >> 6;
    const int wr = w >> 2, wc = w & 3;             // wave: 2 row frags, 4 col frags
    const int l15 = lane & 15, quad = lane >> 4;

    f32x4 acc[2][4] = {};

    // A: 64 rows x 32 ints / stage = 512 int4, one per thread
    const int a_n = t >> 3, a_c4 = t & 7;
    const i32x4* pa4 = (const i32x4*)(adj + (size_t)(m0 + a_n) * 16384 + ky * 8192) + a_c4;
    const int a_lds = a_n * A_STRIDE + a_c4 * 4;

    // B: stage kk = yTt tile (ky*256 + kk): contiguous 16 KB; 2 uint4/thread
    const uint16_t* pB = yTt + (size_t)(ky * 256) * 8192 + t * 8;
    const int b_s0 = t, b_s1 = t + 512;            // slots
    const int b_lds0 = (b_s0 >> 2) * B_STRIDE + (b_s0 & 3) * 8;
    const int b_lds1 = (b_s1 >> 2) * B_STRIDE + (b_s1 & 3) * 8;

    // ---- prologue: load A(0..3) nt, B(0..1); stage 0 -> LDS buf 0
    i32x4 a0 = __builtin_nontemporal_load(pa4);
    i32x4 q1 = __builtin_nontemporal_load(pa4 + 8);    // A(1)
    i32x4 q2 = __builtin_nontemporal_load(pa4 + 16);   // A(2)
    i32x4 q3 = __builtin_nontemporal_load(pa4 + 24);   // A(3)
    i32x4 aN = q3;
    pa4 += 32;
    uint4 b00 = *(const uint4*)(pB);
    uint4 b01 = *(const uint4*)(pB + 4096);
    pB += 8192;
    uint4 bC0 = *(const uint4*)(pB);          // B(1)
    uint4 bC1 = *(const uint4*)(pB + 4096);
    pB += 8192;
    uint4 bN0 = bC0, bN1 = bC1;

    int degp = a0.x + a0.y + a0.z + a0.w;
    {
        uint2 pv;
        pv.x = (uint32_t)(a0.x | (a0.y << 16)) * 0x3F80u;
        pv.y = (uint32_t)(a0.z | (a0.w << 16)) * 0x3F80u;
        *(uint2*)&As0[a_lds] = pv;
        *(uint4*)&Bs0[b_lds0] = b00;
        *(uint4*)&Bs0[b_lds1] = b01;
    }
    asm volatile("s_waitcnt lgkmcnt(0)\n\ts_barrier" ::: "memory");

    // ---- main loop: 84 triples = steps 0..251 (all guards true), tail 252..255
    for (int kk = 0; kk < KITER - 4; kk += 3) {
        STEP(0, 0, 1, 1, kk);
        STEP(1, 1, 2, 2, kk + 1);
        STEP(2, 2, 0, 0, kk + 2);
    }
    STEP(0, 0, 1, 1, 252);
    STEP(1, 1, 2, 2, 253);
    STEP(2, 2, 0, 0, 254);
    STEP(0, 0, 1, 1, 255);

    // partial deg: row a_n owned by 8 consecutive lanes
    degp += __shfl_down(degp, 4);
    degp += __shfl_down(degp, 2);
    degp += __shfl_down(degp, 1);
    if ((t & 7) == 0) degw[ky * 16384 + m0 + a_n] = degp;

    // partial C (C/D layout: col=lane&15, row=quad*4+reg) — non-temporal stores
    float* pc = part + (size_t)ky * 16384 * 256;
#pragma unroll
    for (int fr = 0; fr < 2; ++fr) {
#pragma unroll
        for (int r = 0; r < 4; ++r) {
            int m_l = wr * 32 + fr * 16 + quad * 4 + r;
            size_t mrow = (size_t)(m0 + m_l) * 256;
#pragma unroll
            for (int fc = 0; fc < 4; ++fc) {
                int n_g = wc * 64 + fc * 16 + l15;
                __builtin_nontemporal_store(acc[fr][fc][r], &pc[mrow + n_g]);
            }
        }
    }
}

// ---------------- K3: out = (p0+p1)/(d0+d1) + z
__global__ __launch_bounds__(256) void k_reduce(const float* __restrict__ part,
                                                const int* __restrict__ degw,
                                                const float* __restrict__ z,
                                                float* __restrict__ out) {
    int i4 = blockIdx.x * 256 + threadIdx.x;       // float4 index, 64 per row
    int m = i4 >> 6;
    float4 p0 = ((const float4*)part)[i4];
    float4 p1 = ((const float4*)part)[i4 + 16384 * 64];
    float4 zz = ((const float4*)z)[i4];
    float inv = 1.0f / (float)(degw[m] + degw[16384 + m]);
    float4 o;
    o.x = (p0.x + p1.x) * inv + zz.x;
    o.y = (p0.y + p1.y) * inv + zz.y;
    o.z = (p0.z + p1.z) * inv + zz.z;
    o.w = (p0.w + p1.w) * inv + zz.w;
    ((float4*)out)[i4] = o;
}

extern "C" void kernel_launch(void* const* d_in, const int* in_sizes, int n_in,
                              void* d_out, int out_size, void* d_ws, size_t ws_size,
                              hipStream_t stream) {
    const float* x      = (const float*)d_in[0];
    const int*   adj    = (const int*)d_in[1];
    const float* weight = (const float*)d_in[2];
    const float* bias   = (const float*)d_in[3];
    float* out = (float*)d_out;

    // ws: WT 256KB | yTt 8MB | z 16MB | part 32MB | degw 128KB
    char* wsb = (char*)d_ws;
    uint16_t* wt   = (uint16_t*)(wsb);
    uint16_t* yTt  = (uint16_t*)(wsb + 262144);
    float*    z    = (float*)(wsb + 262144 + 8388608);
    float*    partb= (float*)(wsb + 262144 + 8388608 + 16777216);
    int*      degw = (int*)(wsb + 262144 + 8388608 + 16777216 + 33554432);

    k_transpose_w<<<512, 256, 0, stream>>>(weight, wt);
    k_small_gemm<<<dim3(4, 128), 256, 0, stream>>>(x, wt, bias, yTt, z);
    k_big_gemm<<<dim3(256, 2), 512, 0, stream>>>(adj, yTt, partb, degw);
    k_reduce<<<4096, 256, 0, stream>>>(partb, degw, z, out);
}